// Round 8
// baseline (132.931 us; speedup 1.0000x reference)
//
#include <hip/hip_runtime.h>

static constexpr float ALPHA = 0.1f;

#define TW 64
#define TH 8
// hist window: rows h0-4 .. h0+11 (16 rows), cols w0-8 .. w0+75 (84 cols)
// jitter: |dx| < 4.8 px, |dy| < 2.7 px -> taps within [w-6,w+6] x [h-4,h+4]
#define HROWS 16
#define HCOLS 84          // row stride 84 words (336 B, 16B-aligned rows)
#define CHOFF (HROWS * HCOLS)   // 1344 words; channel byte offset 5376 fits ds imm

__device__ __forceinline__ int iclamp(int v, int lo, int hi) { return min(max(v, lo), hi); }

struct Setup {
    int mA, m1, m2, mB;   // global tap coords (unclamped)
    float t, w0, w3, w12;
};

__device__ __forceinline__ Setup axis_setup(float gcoord, float S) {
    Setup s;
    float pos = (gcoord + 1.0f) * 0.5f * S;
    float pm  = floorf(pos - 0.5f);
    float f   = pos - (pm + 0.5f);
    float f2 = f * f, f3 = f2 * f;
    s.w0  = -0.5f * f3 + f2 - 0.5f * f;
    float w2 = -1.5f * f3 + 2.0f * f2 + 0.5f * f;
    s.w3  =  0.5f * f3 - 0.5f * f2;
    s.w12 = (1.5f * f3 - 2.5f * f2 + 1.0f) + w2;
    float p12 = pm + __fdividef(w2, s.w12);
    float fl  = floorf(p12);
    s.t = p12 - fl;
    int m = (int)pm, i12 = (int)fl;
    s.mA = m - 1; s.m1 = i12; s.m2 = i12 + 1; s.mB = m + 2;
    return s;
}

__global__ __launch_bounds__(256, 8) void taa_kernel(
    const float* __restrict__ x, const float* __restrict__ mv,
    const float* __restrict__ hist, float* __restrict__ out)
{
    constexpr int N = 2, H = 1080, W = 1920, HW = H * W;
    constexpr int NTX = W / TW;          // 30
    constexpr int NTY = H / TH;          // 135
    constexpr int NWG = N * NTX * NTY;   // 8100
    constexpr int Q = NWG / 8, R = NWG % 8;

    __shared__ __align__(16) float Lh[3 * CHOFF];

    // Bijective XCD swizzle: each XCD owns a contiguous band of x-major work
    // ids -> vertically adjacent tiles share an XCD's L2 (FETCH 231->65 MB).
    int d = blockIdx.x;
    int xcd = d & 7, di = d >> 3;
    int work = (xcd < R ? xcd * (Q + 1) : R * (Q + 1) + (xcd - R) * Q) + di;
    int n   = work / (NTX * NTY);
    int rem = work - n * (NTX * NTY);
    int ty  = rem / NTX;
    int tx  = rem - ty * NTX;
    const int w0 = tx * TW, h0 = ty * TH;

    const int lx = threadIdx.x & 63;
    const int wv = threadIdx.x >> 6;      // 0..3; thread owns rows 2wv, 2wv+1
    const int wpix = w0 + lx;
    const int hbase = h0 + 2 * wv;

    const float* hn = hist + n * 3 * HW;
    const float* xn = x    + n * 3 * HW;

    // ---- mv loads (coalesced float2, issue first) ----
    const float2 g0 = ((const float2*)mv)[n * HW + hbase * W + wpix];
    const float2 g1 = ((const float2*)mv)[n * HW + (hbase + 1) * W + wpix];

    // ---- stage history window into LDS ----
    const bool interior = (tx >= 1) && (tx <= NTX - 2) &&
                          (h0 >= 4) && (h0 + TH + 3 <= H - 1);
    if (interior) {
        float4* Lh4 = (float4*)Lh;
        for (int idx = threadIdx.x; idx < 1008; idx += 256) {     // 3*16*21 float4
            int c  = idx / 336;
            int rm = idx - c * 336;
            int r  = rm / 21;
            int c4 = rm - r * 21;
            Lh4[idx] = *(const float4*)(hn + c * HW + (h0 - 4 + r) * W + (w0 - 8) + c4 * 4);
        }
    } else {
        for (int idx = threadIdx.x; idx < 4032; idx += 256) {     // 3*16*84 scalar
            int c  = idx / CHOFF;
            int rm = idx - c * CHOFF;
            int r  = rm / HCOLS;
            int cc = rm - r * HCOLS;
            int gr = iclamp(h0 - 4 + r, 0, H - 1);
            int gc = iclamp(w0 - 8 + cc, 0, W - 1);
            Lh[idx] = hn[c * HW + gr * W + gc];
        }
    }

    // ---- x neighborhood (coalesced VMEM; overlaps staging latency) ----
    int rg0 = iclamp(hbase - 1, 0, H - 1) * W;
    int rg1 = hbase * W;
    int rg2 = (hbase + 1) * W;
    int rg3 = iclamp(hbase + 2, 0, H - 1) * W;
    const int rg[4] = {rg0, rg1, rg2, rg3};

    float hmx[3][4], hmn[3][4], xmid[3][4];
    if (tx >= 1 && tx <= NTX - 2) {
        // interior in x: wpix-1 / wpix+1 valid -> immediate-offset loads
#pragma unroll
        for (int c = 0; c < 3; ++c) {
            const float* xc = xn + c * HW + wpix;
#pragma unroll
            for (int rr = 0; rr < 4; ++rr) {
                const float* p = xc + rg[rr];
                float a = p[-1], b = p[0], e = p[1];
                hmx[c][rr]  = fmaxf(fmaxf(a, b), e);
                hmn[c][rr]  = fminf(fminf(a, b), e);
                xmid[c][rr] = b;
            }
        }
    } else {
        const int wm = max(wpix - 1, 0), wp = min(wpix + 1, W - 1);
#pragma unroll
        for (int c = 0; c < 3; ++c) {
            const float* xc = xn + c * HW;
#pragma unroll
            for (int rr = 0; rr < 4; ++rr) {
                float a = xc[rg[rr] + wm];
                float b = xc[rg[rr] + wpix];
                float e = xc[rg[rr] + wp];
                hmx[c][rr]  = fmaxf(fmaxf(a, b), e);
                hmn[c][rr]  = fminf(fminf(a, b), e);
                xmid[c][rr] = b;
            }
        }
    }

    // ---- bicubic setup for both pixels (overlaps staging latency) ----
    Setup sx0 = axis_setup(g0.x, (float)W);
    Setup sy0 = axis_setup(g0.y, (float)H);
    Setup sx1 = axis_setup(g1.x, (float)W);
    Setup sy1 = axis_setup(g1.y, (float)H);

    __syncthreads();

    float* on = out + n * 3 * HW;

#pragma unroll
    for (int p = 0; p < 2; ++p) {
        const Setup& sx = p ? sx1 : sx0;
        const Setup& sy = p ? sy1 : sy0;

        const int lrA = iclamp(sy.mA - (h0 - 4), 0, HROWS - 1);
        const int lr1 = iclamp(sy.m1 - (h0 - 4), 0, HROWS - 1);
        const int lr2 = iclamp(sy.m2 - (h0 - 4), 0, HROWS - 1);
        const int lrB = iclamp(sy.mB - (h0 - 4), 0, HROWS - 1);
        const int lcA = iclamp(sx.mA - (w0 - 8), 0, HCOLS - 1);
        const int lc1 = iclamp(sx.m1 - (w0 - 8), 0, HCOLS - 1);
        const int lc2 = iclamp(sx.m2 - (w0 - 8), 0, HCOLS - 1);
        const int lcB = iclamp(sx.mB - (w0 - 8), 0, HCOLS - 1);

        // 12 word offsets, shared across channels (channel adds a CONSTANT
        // 5376-byte ds_read immediate offset)
        const int rA = lrA * HCOLS, r1 = lr1 * HCOLS, r2 = lr2 * HCOLS, rB = lrB * HCOLS;
        const int oA1 = rA + lc1, oA2 = rA + lc2;
        const int o1A = r1 + lcA, o11 = r1 + lc1, o12 = r1 + lc2, o1B = r1 + lcB;
        const int o2A = r2 + lcA, o21 = r2 + lc1, o22 = r2 + lc2, o2B = r2 + lcB;
        const int oB1 = rB + lc1, oB2 = rB + lc2;

        const float tx_ = sx.t, ty_ = sy.t;
        const float omtx = 1.0f - tx_, omty = 1.0f - ty_;
        const float ww1 = sx.w12 * sy.w0;
        const float ww2 = sx.w0  * sy.w12;
        const float ww3 = sx.w3  * sy.w12;
        const float ww4 = sx.w12 * sy.w3;
        const float ww5 = sx.w12 * sy.w12;
        const float rrec = __fdividef(1.0f, ww1 + ww2 + ww3 + ww4 + ww5);

        const int gpix = (hbase + p) * W + wpix;

#pragma unroll
        for (int c = 0; c < 3; ++c) {
            const float* L = Lh + c * CHOFF;
            float s1   = L[oA1] * omtx + L[oA2] * tx_;
            float s4   = L[oB1] * omtx + L[oB2] * tx_;
            float s2   = L[o1A] * omty + L[o2A] * ty_;
            float s3   = L[o1B] * omty + L[o2B] * ty_;
            float top5 = L[o11] * omtx + L[o12] * tx_;
            float bot5 = L[o21] * omtx + L[o22] * tx_;
            float s5   = top5 * omty + bot5 * ty_;
            float reproj = (s1 * ww1 + s2 * ww2 + s3 * ww3 + s4 * ww4 + s5 * ww5) * rrec;

            float mxv = fmaxf(fmaxf(hmx[c][p], hmx[c][p + 1]), hmx[c][p + 2]);
            float mnv = fminf(fminf(hmn[c][p], hmn[c][p + 1]), hmn[c][p + 2]);
            reproj = fminf(fmaxf(reproj, mnv), mxv);

            on[c * HW + gpix] = ALPHA * xmid[c][p + 1] + (1.0f - ALPHA) * reproj;
        }
    }
}

extern "C" void kernel_launch(void* const* d_in, const int* in_sizes, int n_in,
                              void* d_out, int out_size, void* d_ws, size_t ws_size,
                              hipStream_t stream) {
    const float* x    = (const float*)d_in[0];
    const float* mv   = (const float*)d_in[1];
    const float* hist = (const float*)d_in[2];
    float* out = (float*)d_out;

    constexpr int NWG = 2 * (1920 / TW) * (1080 / TH);  // 8100
    taa_kernel<<<dim3(NWG, 1, 1), dim3(256, 1, 1), 0, stream>>>(x, mv, hist, out);
}

// Round 9
// 50.354 us; speedup vs baseline: 2.6399x; 2.6399x over previous
//
#include <hip/hip_runtime.h>

static constexpr float ALPHA = 0.1f;

typedef _Float16 h2 __attribute__((ext_vector_type(2)));

#define TW 64
#define TH 8
// hist window: rows h0-4 .. h0+11 (16 rows), cols w0-8 .. w0+75 (84 data cols)
// jitter: |dx| < 4.8 px, |dy| < 2.7 px -> taps within [w-6,w+6] x [h-4,h+4]
// LDS layout: word i of a row = packed f16 pair (h[i], h[i+1])  (overlapping)
#define HROWS 16
#define HCOLS 84                 // words per row (336 B, 16B-aligned)
#define CHOFF (HROWS * HCOLS)    // 1344 words; channel byte offset 5376 fits ds imm

__device__ __forceinline__ int iclamp(int v, int lo, int hi) { return min(max(v, lo), hi); }

__device__ __forceinline__ unsigned pk(float a, float b) {
    return __builtin_bit_cast(unsigned, __builtin_amdgcn_cvt_pkrtz(a, b));
}
__device__ __forceinline__ float dot2(unsigned a, unsigned b, float c) {
    return __builtin_amdgcn_fdot2(__builtin_bit_cast(h2, a), __builtin_bit_cast(h2, b), c, false);
}

struct Setup {
    int mA, m1, m2, mB;   // global tap coords (unclamped)
    float t, w0, w3, w12;
};

__device__ __forceinline__ Setup axis_setup(float gcoord, float S) {
    Setup s;
    float pos = (gcoord + 1.0f) * 0.5f * S;
    float pm  = floorf(pos - 0.5f);
    float f   = pos - (pm + 0.5f);
    float f2 = f * f, f3 = f2 * f;
    s.w0  = -0.5f * f3 + f2 - 0.5f * f;
    float w2 = -1.5f * f3 + 2.0f * f2 + 0.5f * f;
    s.w3  =  0.5f * f3 - 0.5f * f2;
    s.w12 = (1.5f * f3 - 2.5f * f2 + 1.0f) + w2;
    float p12 = pm + __fdividef(w2, s.w12);
    float fl  = floorf(p12);
    s.t = p12 - fl;
    int m = (int)pm, i12 = (int)fl;
    s.mA = m - 1; s.m1 = i12; s.m2 = i12 + 1; s.mB = m + 2;
    return s;
}

__global__ __launch_bounds__(256, 4) void taa_kernel(
    const float* __restrict__ x, const float* __restrict__ mv,
    const float* __restrict__ hist, float* __restrict__ out)
{
    constexpr int N = 2, H = 1080, W = 1920, HW = H * W;
    constexpr int NTX = W / TW;          // 30
    constexpr int NTY = H / TH;          // 135
    constexpr int NWG = N * NTX * NTY;   // 8100
    constexpr int Q = NWG / 8, R = NWG % 8;

    __shared__ __align__(16) unsigned Lh[3 * CHOFF];

    // Bijective XCD swizzle: each XCD owns a contiguous band of x-major work
    // ids -> vertically adjacent tiles share an XCD's L2 (FETCH 231->65 MB).
    int d = blockIdx.x;
    int xcd = d & 7, di = d >> 3;
    int work = (xcd < R ? xcd * (Q + 1) : R * (Q + 1) + (xcd - R) * Q) + di;
    int n   = work / (NTX * NTY);
    int rem = work - n * (NTX * NTY);
    int ty  = rem / NTX;
    int tx  = rem - ty * NTX;
    const int w0 = tx * TW, h0 = ty * TH;

    const int lx = threadIdx.x & 63;
    const int wv = threadIdx.x >> 6;      // 0..3; thread owns rows 2wv, 2wv+1
    const int wpix = w0 + lx;
    const int hbase = h0 + 2 * wv;

    const float* hn = hist + n * 3 * HW;
    const float* xn = x    + n * 3 * HW;

    // ---- mv loads (coalesced float2, issue first) ----
    const float2 g0 = ((const float2*)mv)[n * HW + hbase * W + wpix];
    const float2 g1 = ((const float2*)mv)[n * HW + (hbase + 1) * W + wpix];

    // ---- stage history window into LDS as overlapping f16 pairs ----
    const bool interior = (tx >= 1) && (tx <= NTX - 2) &&
                          (h0 >= 4) && (h0 + TH + 3 <= H - 1);
    if (interior) {
        for (int idx = threadIdx.x; idx < 1008; idx += 256) {     // 3*16*21 groups
            int c  = idx / 336;
            int rm = idx - c * 336;
            int r  = rm / 21;
            int c4 = rm - r * 21;
            const float* src = hn + c * HW + (h0 - 4 + r) * W + (w0 - 8) + c4 * 4;
            const float4 v = *(const float4*)src;
            const float v4 = src[4];                              // col+4 (in-bounds)
            uint4 pw;
            pw.x = pk(v.x, v.y);
            pw.y = pk(v.y, v.z);
            pw.z = pk(v.z, v.w);
            pw.w = pk(v.w, v4);
            *(uint4*)(Lh + c * CHOFF + r * HCOLS + c4 * 4) = pw;  // 16B-aligned
        }
    } else {
        for (int idx = threadIdx.x; idx < 4032; idx += 256) {     // 3*16*84 words
            int c  = idx / CHOFF;
            int rm = idx - c * CHOFF;
            int r  = rm / HCOLS;
            int cc = rm - r * HCOLS;
            int gr  = iclamp(h0 - 4 + r, 0, H - 1);
            int gc0 = iclamp(w0 - 8 + cc,     0, W - 1);
            int gc1 = iclamp(w0 - 8 + cc + 1, 0, W - 1);
            const float* row = hn + c * HW + gr * W;
            Lh[idx] = pk(row[gc0], row[gc1]);
        }
    }

    // ---- x neighborhood (coalesced VMEM; overlaps staging latency) ----
    int rg0 = iclamp(hbase - 1, 0, H - 1) * W;
    int rg1 = hbase * W;
    int rg2 = (hbase + 1) * W;
    int rg3 = iclamp(hbase + 2, 0, H - 1) * W;
    const int rg[4] = {rg0, rg1, rg2, rg3};

    float hmx[3][4], hmn[3][4], xmid[3][4];
    if (tx >= 1 && tx <= NTX - 2) {
#pragma unroll
        for (int c = 0; c < 3; ++c) {
            const float* xc = xn + c * HW + wpix;
#pragma unroll
            for (int rr = 0; rr < 4; ++rr) {
                const float* p = xc + rg[rr];
                float a = p[-1], b = p[0], e = p[1];
                hmx[c][rr]  = fmaxf(fmaxf(a, b), e);
                hmn[c][rr]  = fminf(fminf(a, b), e);
                xmid[c][rr] = b;
            }
        }
    } else {
        const int wm = max(wpix - 1, 0), wp = min(wpix + 1, W - 1);
#pragma unroll
        for (int c = 0; c < 3; ++c) {
            const float* xc = xn + c * HW;
#pragma unroll
            for (int rr = 0; rr < 4; ++rr) {
                float a = xc[rg[rr] + wm];
                float b = xc[rg[rr] + wpix];
                float e = xc[rg[rr] + wp];
                hmx[c][rr]  = fmaxf(fmaxf(a, b), e);
                hmn[c][rr]  = fminf(fminf(a, b), e);
                xmid[c][rr] = b;
            }
        }
    }

    // ---- bicubic setup for both pixels (overlaps staging latency) ----
    Setup sx0 = axis_setup(g0.x, (float)W);
    Setup sy0 = axis_setup(g0.y, (float)H);
    Setup sx1 = axis_setup(g1.x, (float)W);
    Setup sy1 = axis_setup(g1.y, (float)H);

    __syncthreads();

    float* on = out + n * 3 * HW;

#pragma unroll
    for (int p = 0; p < 2; ++p) {
        const Setup& sx = p ? sx1 : sx0;
        const Setup& sy = p ? sy1 : sy0;

        const int lrA = iclamp(sy.mA - (h0 - 4), 0, HROWS - 1);
        const int lr1 = iclamp(sy.m1 - (h0 - 4), 0, HROWS - 1);
        const int lr2 = iclamp(sy.m2 - (h0 - 4), 0, HROWS - 1);
        const int lrB = iclamp(sy.mB - (h0 - 4), 0, HROWS - 1);
        const int lcA = iclamp(sx.mA - (w0 - 8), 0, HCOLS - 1);
        const int lc1 = iclamp(sx.m1 - (w0 - 8), 0, HCOLS - 1);
        const int lcB = iclamp(sx.mB - (w0 - 8), 0, HCOLS - 1);

        // 8 word offsets, shared across channels (channel adds a CONSTANT
        // 5376-byte ds_read immediate offset)
        const int rA = lrA * HCOLS, r1 = lr1 * HCOLS, r2 = lr2 * HCOLS, rB = lrB * HCOLS;
        const int oA  = rA + lc1;   // s1 horizontal pair
        const int oB  = rB + lc1;   // s4 horizontal pair
        const int oC1 = r1 + lc1;   // s5 top pair
        const int oC2 = r2 + lc1;   // s5 bottom pair
        const int oL1 = r1 + lcA;   // s2 (low halves of two rows)
        const int oL2 = r2 + lcA;
        const int oR1 = r1 + lcB;   // s3
        const int oR2 = r2 + lcB;

        const float tx_ = sx.t, ty_ = sy.t;
        const float omtx = 1.0f - tx_, omty = 1.0f - ty_;
        const unsigned wx   = pk(omtx, tx_);
        const unsigned wy   = pk(omty, ty_);
        const unsigned wtop = pk(omtx * omty, tx_ * omty);
        const unsigned wbot = pk(omtx * ty_,  tx_ * ty_);

        const float ww1 = sx.w12 * sy.w0;
        const float ww2 = sx.w0  * sy.w12;
        const float ww3 = sx.w3  * sy.w12;
        const float ww4 = sx.w12 * sy.w3;
        const float ww5 = sx.w12 * sy.w12;
        const float rrec = __fdividef(1.0f, ww1 + ww2 + ww3 + ww4 + ww5);

        const int gpix = (hbase + p) * W + wpix;

#pragma unroll
        for (int c = 0; c < 3; ++c) {
            const unsigned* L = Lh + c * CHOFF;
            unsigned wA  = L[oA],  wB  = L[oB];
            unsigned wc1 = L[oC1], wc2 = L[oC2];
            unsigned wl1 = L[oL1], wl2 = L[oL2];
            unsigned wr1 = L[oR1], wr2 = L[oR2];

            float s1 = dot2(wA, wx, 0.0f);
            float s4 = dot2(wB, wx, 0.0f);
            float s5 = dot2(wc1, wtop, dot2(wc2, wbot, 0.0f));
            // combine low halves of the two row-words -> (h[r1], h[r2])
            unsigned pl = __builtin_amdgcn_perm(wl1, wl2, 0x01000504u);
            unsigned pr = __builtin_amdgcn_perm(wr1, wr2, 0x01000504u);
            float s2 = dot2(pl, wy, 0.0f);
            float s3 = dot2(pr, wy, 0.0f);

            float reproj = (s1 * ww1 + s2 * ww2 + s3 * ww3 + s4 * ww4 + s5 * ww5) * rrec;

            float mxv = fmaxf(fmaxf(hmx[c][p], hmx[c][p + 1]), hmx[c][p + 2]);
            float mnv = fminf(fminf(hmn[c][p], hmn[c][p + 1]), hmn[c][p + 2]);
            reproj = fminf(fmaxf(reproj, mnv), mxv);

            on[c * HW + gpix] = ALPHA * xmid[c][p + 1] + (1.0f - ALPHA) * reproj;
        }
    }
}

extern "C" void kernel_launch(void* const* d_in, const int* in_sizes, int n_in,
                              void* d_out, int out_size, void* d_ws, size_t ws_size,
                              hipStream_t stream) {
    const float* x    = (const float*)d_in[0];
    const float* mv   = (const float*)d_in[1];
    const float* hist = (const float*)d_in[2];
    float* out = (float*)d_out;

    constexpr int NWG = 2 * (1920 / TW) * (1080 / TH);  // 8100
    taa_kernel<<<dim3(NWG, 1, 1), dim3(256, 1, 1), 0, stream>>>(x, mv, hist, out);
}